// Round 3
// baseline (289.394 us; speedup 1.0000x reference)
//
#include <hip/hip_runtime.h>
#include <math.h>

// Problem constants
#define BB 8
#define LL 512
#define HH 768
#define PP 5
#define MM 32
#define DD 256
#define BL (BB*LL)          // 4096 rows
#define NCAT (3*HH)         // 2304 GEMM output cols
#define NSC (LL*PP)         // 2560 scores per batch
#define GK HH               // per-term K = 768

typedef short short8_t __attribute__((ext_vector_type(8)));
typedef float floatx4  __attribute__((ext_vector_type(4)));

// ---------------------------------------------------------------------------
// bf16 helpers (RNE)
__device__ __forceinline__ unsigned short f2bf_rne(float x) {
    unsigned u = __float_as_uint(x);
    unsigned r = u + 0x7FFFu + ((u >> 16) & 1u);
    return (unsigned short)(r >> 16);
}
__device__ __forceinline__ void split3(float x, unsigned short& s0,
                                       unsigned short& s1, unsigned short& s2) {
    unsigned short h0 = f2bf_rne(x);
    float f0 = __uint_as_float((unsigned)h0 << 16);
    float r1 = x - f0;
    unsigned short h1 = f2bf_rne(r1);
    float f1 = __uint_as_float((unsigned)h1 << 16);
    float r2 = r1 - f1;
    unsigned short h2 = f2bf_rne(r2);
    s0 = h0; s1 = h1; s2 = h2;
}

// ---------------------------------------------------------------------------
// lengths + n_valid per batch
__global__ __launch_bounds__(256) void prep_lengths(const int* __restrict__ mask,
                                                    int* __restrict__ lengths,
                                                    int* __restrict__ nvalid) {
    int b = blockIdx.x;
    int t = threadIdx.x;
    int v = mask[b*LL + t] + mask[b*LL + 256 + t];
    #pragma unroll
    for (int off = 32; off; off >>= 1) v += __shfl_xor(v, off);
    __shared__ int red[4];
    if ((t & 63) == 0) red[t >> 6] = v;
    __syncthreads();
    if (t == 0) {
        int len = red[0] + red[1] + red[2] + red[3];
        lengths[b] = len;
        int nv = 0;
        #pragma unroll
        for (int p = 0; p < PP; ++p) nv += (len - p > 0) ? (len - p) : 0;
        nvalid[b] = nv;
    }
}

// ---------------------------------------------------------------------------
// A-splits: hidden (4096x768 f32) -> Aspl[3][4096][768] bf16
__global__ __launch_bounds__(256) void build_asplit(const float* __restrict__ hidden,
                                                    unsigned short* __restrict__ Aspl) {
    const size_t PLANE = (size_t)BL * GK;
    size_t base = ((size_t)blockIdx.x * 256 + threadIdx.x) * 4;
    float4 v = *(const float4*)(hidden + base);
    ushort4 p0, p1, p2;
    split3(v.x, p0.x, p1.x, p2.x);
    split3(v.y, p0.y, p1.y, p2.y);
    split3(v.z, p0.z, p1.z, p2.z);
    split3(v.w, p0.w, p1.w, p2.w);
    *(ushort4*)(Aspl + base)             = p0;
    *(ushort4*)(Aspl + PLANE + base)     = p1;
    *(ushort4*)(Aspl + 2 * PLANE + base) = p2;
}

// ---------------------------------------------------------------------------
// B-splits, TRANSPOSED: Bspl[3][2304 n][768 k] bf16, built directly from W1.
__global__ __launch_bounds__(256) void build_bsplit(const float* __restrict__ W1,
                                                    unsigned short* __restrict__ Bspl) {
    const size_t PLANE = (size_t)NCAT * GK;
    __shared__ float wv[16][65];
    int n0 = blockIdx.x * 16;
    int k0 = blockIdx.y * 64;
    int tx = threadIdx.x & 15;   // n offset (coalesced W1 read)
    int ty = threadIdx.x >> 4;   // k-quad
    int n = n0 + tx;
    #pragma unroll
    for (int j = 0; j < 4; ++j) {
        int k = k0 + ty * 4 + j;
        float w;
        if (n < HH) {
            w = W1[(size_t)k * HH + n] - W1[(size_t)(3*HH + k) * HH + n];
        } else if (n < 2 * HH) {
            int c = n - HH;
            w = W1[(size_t)(HH + k) * HH + c] + W1[(size_t)(3*HH + k) * HH + c];
        } else {
            int c = n - 2 * HH;
            w = W1[(size_t)(2*HH + k) * HH + c];
        }
        wv[tx][ty * 4 + j] = w;
    }
    __syncthreads();
    int n2 = threadIdx.x >> 4;   // 0..15
    int kq = threadIdx.x & 15;   // 0..15 (coalesced Bspl write)
    unsigned short e0[4], e1[4], e2[4];
    #pragma unroll
    for (int j = 0; j < 4; ++j)
        split3(wv[n2][kq * 4 + j], e0[j], e1[j], e2[j]);
    size_t off = (size_t)(n0 + n2) * GK + k0 + kq * 4;
    *(ushort4*)(Bspl + off)             = make_ushort4(e0[0], e0[1], e0[2], e0[3]);
    *(ushort4*)(Bspl + PLANE + off)     = make_ushort4(e1[0], e1[1], e1[2], e1[3]);
    *(ushort4*)(Bspl + 2 * PLANE + off) = make_ushort4(e2[0], e2[1], e2[2], e2[3]);
}

// ---------------------------------------------------------------------------
// bf16x3-split MFMA GEMM: XO = sum over 6 term-products of Aspl x Bspl^T
// 128x128 tile, BK=64, 2 waves, per-wave tile 64x128 (A-frag reused over 8
// B-frags -> MFMA-bound, not DS-bound). mfma_f32_16x16x32_bf16.
// XOR slot-swizzle slot^(row&7); global_load_lds w=16 with pre-swizzled src.
__global__ __launch_bounds__(128, 2) void gemm_mfma(const unsigned short* __restrict__ Aspl,
                                                    const unsigned short* __restrict__ Bspl,
                                                    float* __restrict__ C) {
    __shared__ __align__(16) unsigned short Asm[128 * 64];
    __shared__ __align__(16) unsigned short Bsm[128 * 64];
    const int tid  = threadIdx.x;
    const int wave = tid >> 6;           // 0..1
    const int lane = tid & 63;
    const int m0 = blockIdx.x * 128;
    const int n0 = blockIdx.y * 128;
    const int srow = lane >> 3;          // 0..7 (row within 8-row stage group)
    const int slog = (lane & 7) ^ srow;  // logical k-slot this lane fetches
    const int l15 = lane & 15;
    const int g   = lane >> 4;           // 0..3
    const int r7  = l15 & 7;

    floatx4 acc[4][8];
    #pragma unroll
    for (int i = 0; i < 4; ++i)
        #pragma unroll
        for (int j = 0; j < 8; ++j) acc[i][j] = (floatx4)0.f;

    const size_t APL = (size_t)BL * GK;
    const size_t BPL = (size_t)NCAT * GK;

    #pragma unroll 1
    for (int t = 0; t < 6; ++t) {
        // term selects: a = {0,0,1,1,0,2}, b = {0,1,0,1,2,0}
        const int a_sel = (t < 4) ? (t >> 1) : ((t == 4) ? 0 : 2);
        const int b_sel = (t < 4) ? (t & 1)  : ((t == 4) ? 2 : 0);
        const unsigned short* Ab = Aspl + (size_t)a_sel * APL + (size_t)m0 * GK;
        const unsigned short* Bb = Bspl + (size_t)b_sel * BPL + (size_t)n0 * GK;
        #pragma unroll 1
        for (int kt = 0; kt < GK; kt += 64) {
            __syncthreads();   // previous compute done before overwrite
            // stage A and B: 16 row-groups of 8 rows each; wave w takes groups
            // with (group & 1) == w. Each issue writes 8 rows x 128B linear.
            #pragma unroll
            for (int j = 0; j < 8; ++j) {
                int grp = j * 2 + wave;
                int base_r = grp * 8;
                const unsigned short* sa = Ab + (size_t)(base_r + srow) * GK + kt + slog * 8;
                __builtin_amdgcn_global_load_lds(
                    (const __attribute__((address_space(1))) void*)sa,
                    (__attribute__((address_space(3))) void*)&Asm[base_r * 64],
                    16, 0, 0);
                const unsigned short* sb = Bb + (size_t)(base_r + srow) * GK + kt + slog * 8;
                __builtin_amdgcn_global_load_lds(
                    (const __attribute__((address_space(1))) void*)sb,
                    (__attribute__((address_space(3))) void*)&Bsm[base_r * 64],
                    16, 0, 0);
            }
            __syncthreads();   // vmcnt(0) drained before barrier by compiler
            #pragma unroll
            for (int ks = 0; ks < 2; ++ks) {
                const int sph = ((ks * 4 + g) ^ r7) * 8;
                short8_t afr[4], bfr[8];
                #pragma unroll
                for (int mf = 0; mf < 4; ++mf)
                    afr[mf] = *(const short8_t*)&Asm[(wave * 64 + mf * 16 + l15) * 64 + sph];
                #pragma unroll
                for (int nf = 0; nf < 8; ++nf)
                    bfr[nf] = *(const short8_t*)&Bsm[(nf * 16 + l15) * 64 + sph];
                #pragma unroll
                for (int mf = 0; mf < 4; ++mf)
                    #pragma unroll
                    for (int nf = 0; nf < 8; ++nf)
                        acc[mf][nf] = __builtin_amdgcn_mfma_f32_16x16x32_bf16(
                            afr[mf], bfr[nf], acc[mf][nf], 0, 0, 0);
            }
        }
    }
    // epilogue: D row = (lane>>4)*4 + reg, col = lane&15 (m89-verified layout)
    #pragma unroll
    for (int mf = 0; mf < 4; ++mf) {
        #pragma unroll
        for (int nf = 0; nf < 8; ++nf) {
            int col  = n0 + nf * 16 + l15;
            int rowb = m0 + wave * 64 + mf * 16 + g * 4;
            #pragma unroll
            for (int e = 0; e < 4; ++e)
                C[(size_t)(rowb + e) * NCAT + col] = acc[mf][nf][e];
        }
    }
}

// ---------------------------------------------------------------------------
// scores(b,l,p) = w2 . relu(XA[l] + XB[l+p] + (sum_{t=l..l+p} Y[t])/(p+1) + b1) + b2
// one wave per (b,l); invalid -> -inf
__global__ __launch_bounds__(256) void score_kernel(const float* __restrict__ XO,
                                                    const float* __restrict__ b1,
                                                    const float* __restrict__ w2,
                                                    const float* __restrict__ b2,
                                                    const int* __restrict__ lengths,
                                                    float* __restrict__ sc) {
    int wid = (blockIdx.x * blockDim.x + threadIdx.x) >> 6;  // 0..4095
    int lane = threadIdx.x & 63;
    int b = wid >> 9, l = wid & (LL - 1);
    int len = lengths[b];
    float b2v = b2[0];

    const float* rowXA = XO + (size_t)wid * NCAT;
    float xa[12], sv[12], w2v[12];
    #pragma unroll
    for (int seg = 0; seg < 3; ++seg) {
        int h = seg * 256 + lane * 4;
        float4 a  = *(const float4*)(rowXA + h);
        float4 bb = *(const float4*)(b1 + h);
        float4 w  = *(const float4*)(w2 + h);
        xa[seg*4+0] = a.x + bb.x; xa[seg*4+1] = a.y + bb.y;
        xa[seg*4+2] = a.z + bb.z; xa[seg*4+3] = a.w + bb.w;
        w2v[seg*4+0] = w.x; w2v[seg*4+1] = w.y; w2v[seg*4+2] = w.z; w2v[seg*4+3] = w.w;
        sv[seg*4+0] = 0.f; sv[seg*4+1] = 0.f; sv[seg*4+2] = 0.f; sv[seg*4+3] = 0.f;
    }

    for (int p = 0; p < PP; ++p) {
        int j = l + p;
        float res = -INFINITY;
        if (j < len) {  // wave-uniform
            const float* rowj = XO + (size_t)(b * LL + j) * NCAT;
            float rs = 1.0f / (float)(p + 1);
            float part = 0.f;
            #pragma unroll
            for (int seg = 0; seg < 3; ++seg) {
                int h = seg * 256 + lane * 4;
                float4 xb = *(const float4*)(rowj + HH + h);
                float4 yv = *(const float4*)(rowj + 2*HH + h);
                sv[seg*4+0] += yv.x; sv[seg*4+1] += yv.y;
                sv[seg*4+2] += yv.z; sv[seg*4+3] += yv.w;
                float xbv[4] = {xb.x, xb.y, xb.z, xb.w};
                #pragma unroll
                for (int q = 0; q < 4; ++q) {
                    float pre = xa[seg*4+q] + xbv[q] + sv[seg*4+q] * rs;
                    part += fmaxf(pre, 0.f) * w2v[seg*4+q];
                }
            }
            #pragma unroll
            for (int off = 32; off; off >>= 1) part += __shfl_xor(part, off);
            res = part + b2v;
        }
        if (lane == 0) sc[(size_t)wid * PP + p] = res;
    }
}

// ---------------------------------------------------------------------------
// top-32 per batch: 1 wave, 64-bit keys in LDS, 40-chunk max hierarchy,
// fully wave-synchronous (no __syncthreads). Ties -> lower index (lax.top_k).
__device__ __forceinline__ unsigned long long wave_max_ull(unsigned long long v) {
    #pragma unroll
    for (int off = 32; off; off >>= 1) {
        unsigned long long o = __shfl_xor(v, off);
        if (o > v) v = o;
    }
    return v;
}
__global__ __launch_bounds__(64) void topk_kernel(const float* __restrict__ sc,
                                                  int* __restrict__ top_idx,
                                                  float* __restrict__ top_scores) {
    int b = blockIdx.x;
    int lane = threadIdx.x;
    __shared__ unsigned long long key[NSC];   // 20 KB
    __shared__ unsigned long long cmax[40];
    const float* scb = sc + (size_t)b * NSC;
    // load + encode + per-chunk max (chunk j = elements [j*64, j*64+64))
    for (int j = 0; j < 40; ++j) {
        int i = j * 64 + lane;
        unsigned u = __float_as_uint(scb[i]);
        u = (u & 0x80000000u) ? ~u : (u | 0x80000000u);
        unsigned long long k = ((unsigned long long)u << 32) | (unsigned)(0xFFFFFFFFu - i);
        key[i] = k;
        unsigned long long mx = wave_max_ull(k);
        if (lane == 0) cmax[j] = mx;
    }
    for (int m = 0; m < MM; ++m) {
        unsigned long long v = (lane < 40) ? cmax[lane] : 0ull;
        unsigned long long best = wave_max_ull(v);
        int idx = (int)(0xFFFFFFFFu - (unsigned)(best & 0xFFFFFFFFull));
        if (lane == 0) {
            top_idx[b * MM + m]    = idx;
            top_scores[b * MM + m] = scb[idx];
            key[idx] = 0ull;
        }
        // rebuild the affected chunk's max
        int c0 = idx >> 6;
        unsigned long long v2 = key[c0 * 64 + lane];
        unsigned long long mx2 = wave_max_ull(v2);
        if (lane == 0) cmax[c0] = mx2;
    }
}

// ---------------------------------------------------------------------------
// fused tail: per (b,m): feat (mean rows of hidden) -> LDS, then
// gate[b,m] = wg2 . tanh(feat @ Wg1 + bg1) + bg2 and
// embeds[b,m,:] = feat @ Wp + bp
__global__ __launch_bounds__(256) void tail_kernel(const float* __restrict__ hidden,
                                                   const int* __restrict__ top_idx,
                                                   const int* __restrict__ nvalid,
                                                   const float* __restrict__ Wg1,
                                                   const float* __restrict__ bg1,
                                                   const float* __restrict__ wg2,
                                                   const float* __restrict__ bg2,
                                                   const float* __restrict__ Wp,
                                                   const float* __restrict__ bp,
                                                   float* __restrict__ gate,
                                                   float* __restrict__ out_embeds) {
    int bm = blockIdx.x;            // 0..255
    int b = bm >> 5, m = bm & 31;
    int tid = threadIdx.x;
    __shared__ float f[HH];
    __shared__ float red[4];
    int idx = top_idx[bm];
    int l = idx / PP, p = idx % PP;
    bool maskon = (m < nvalid[b]);
    float rs = 1.0f / (float)(p + 1);
    for (int h = tid; h < HH; h += 256) {
        float sum = 0.f;
        if (maskon) {
            for (int t = l; t <= l + p; ++t)
                sum += hidden[((size_t)b * LL + t) * HH + h];
            sum *= rs;
        }
        f[h] = sum;
    }
    __syncthreads();
    // gate partial
    float part = 0.f;
    for (int gg = tid; gg < HH/2; gg += 256) {
        float acc = bg1[gg];
        #pragma unroll 8
        for (int k = 0; k < HH; ++k)
            acc = fmaf(f[k], Wg1[(size_t)k * (HH/2) + gg], acc);
        part += tanhf(acc) * wg2[gg];
    }
    #pragma unroll
    for (int off = 32; off; off >>= 1) part += __shfl_xor(part, off);
    if ((tid & 63) == 0) red[tid >> 6] = part;
    // embed: thread d = tid
    float acc = bp[tid];
    #pragma unroll 8
    for (int k = 0; k < HH; ++k)
        acc = fmaf(f[k], Wp[(size_t)k * DD + tid], acc);
    out_embeds[(size_t)bm * DD + tid] = acc;
    __syncthreads();
    if (tid == 0) gate[bm] = red[0] + red[1] + red[2] + red[3] + bg2[0];
}

// ---------------------------------------------------------------------------
// masks, masked softmax of gate, masked scores
__global__ __launch_bounds__(64) void finalize_kernel(const float* __restrict__ gate,
                                                      const float* __restrict__ top_scores,
                                                      const int* __restrict__ nvalid,
                                                      float* __restrict__ out_masks,
                                                      float* __restrict__ out_attn,
                                                      float* __restrict__ out_scores) {
    int b = blockIdx.x;
    int t = threadIdx.x;
    bool live = (t < MM);
    bool maskon = live && (t < nvalid[b]);
    float g = maskon ? gate[b * MM + t] : -INFINITY;
    float mx = g;
    #pragma unroll
    for (int off = 16; off; off >>= 1) mx = fmaxf(mx, __shfl_xor(mx, off));
    float e = (g == -INFINITY) ? 0.f : expf(g - mx);
    float ssum = e;
    #pragma unroll
    for (int off = 16; off; off >>= 1) ssum += __shfl_xor(ssum, off);
    if (live) {
        out_masks[b * MM + t]  = maskon ? 1.0f : 0.0f;
        out_attn[b * MM + t]   = e / ssum;
        out_scores[b * MM + t] = maskon ? top_scores[b * MM + t] : -INFINITY;
    }
}

// ---------------------------------------------------------------------------
extern "C" void kernel_launch(void* const* d_in, const int* in_sizes, int n_in,
                              void* d_out, int out_size, void* d_ws, size_t ws_size,
                              hipStream_t stream) {
    const float* hidden = (const float*)d_in[0];
    const int*   amask  = (const int*)  d_in[1];
    const float* W1     = (const float*)d_in[2];
    const float* b1     = (const float*)d_in[3];
    const float* w2     = (const float*)d_in[4];
    const float* b2     = (const float*)d_in[5];
    const float* Wg1    = (const float*)d_in[6];
    const float* bg1    = (const float*)d_in[7];
    const float* wg2    = (const float*)d_in[8];
    const float* bg2    = (const float*)d_in[9];
    const float* Wp     = (const float*)d_in[10];
    const float* bp     = (const float*)d_in[11];

    float* out = (float*)d_out;
    float* out_embeds = out;                       // 8*32*256 = 65536
    float* out_masks  = out + 65536;               // 256
    float* out_attn   = out + 65792;               // 256
    float* out_scores = out + 66048;               // 256

    // workspace layout
    unsigned short* Aspl = (unsigned short*)d_ws;              // 3*4096*768 bf16
    unsigned short* Bspl = Aspl + (size_t)3 * BL * GK;         // 3*2304*768 bf16
    float* XO     = (float*)(Bspl + (size_t)3 * NCAT * GK);    // 4096*2304 f32
    float* scbuf  = XO + (size_t)BL * NCAT;                    // 8*2560
    float* gate   = scbuf + (size_t)BB * NSC;                  // 256
    float* tscore = gate + BB * MM;                            // 256
    int*   tidx    = (int*)(tscore + BB * MM);                 // 256
    int*   lengths = tidx + BB * MM;                           // 8
    int*   nvalid  = lengths + BB;                             // 8

    prep_lengths<<<BB, 256, 0, stream>>>(amask, lengths, nvalid);

    build_asplit<<<(BL * GK / 4) / 256, 256, 0, stream>>>(hidden, Aspl);

    {
        dim3 grid(NCAT / 16, GK / 64);   // 144 x 12
        build_bsplit<<<grid, 256, 0, stream>>>(W1, Bspl);
    }

    {
        dim3 grid(BL / 128, NCAT / 128);   // 32 x 18
        gemm_mfma<<<grid, 128, 0, stream>>>(Aspl, Bspl, XO);
    }

    score_kernel<<<(BL * 64) / 256, 256, 0, stream>>>(XO, b1, w2, b2, lengths, scbuf);

    topk_kernel<<<BB, 64, 0, stream>>>(scbuf, tidx, tscore);

    tail_kernel<<<BB * MM, 256, 0, stream>>>(hidden, tidx, nvalid,
                                             Wg1, bg1, wg2, bg2, Wp, bp,
                                             gate, out_embeds);

    finalize_kernel<<<BB, 64, 0, stream>>>(gate, tscore, nvalid, out_masks, out_attn, out_scores);
}

// Round 4
// 270.728 us; speedup vs baseline: 1.0689x; 1.0689x over previous
//
#include <hip/hip_runtime.h>
#include <math.h>

// Problem constants
#define BB 8
#define LL 512
#define HH 768
#define PP 5
#define MM 32
#define DD 256
#define BL (BB*LL)          // 4096 rows
#define NCAT (3*HH)         // 2304 GEMM output cols
#define NSC (LL*PP)         // 2560 scores per batch
#define GK HH               // per-term K = 768
#define NTAIL 640           // tail GEMM cols: 384 gate + 256 embed

typedef short short8_t __attribute__((ext_vector_type(8)));
typedef float floatx4  __attribute__((ext_vector_type(4)));

// ---------------------------------------------------------------------------
// bf16 helpers (RNE)
__device__ __forceinline__ unsigned short f2bf_rne(float x) {
    unsigned u = __float_as_uint(x);
    unsigned r = u + 0x7FFFu + ((u >> 16) & 1u);
    return (unsigned short)(r >> 16);
}
__device__ __forceinline__ void split3(float x, unsigned short& s0,
                                       unsigned short& s1, unsigned short& s2) {
    unsigned short h0 = f2bf_rne(x);
    float f0 = __uint_as_float((unsigned)h0 << 16);
    float r1 = x - f0;
    unsigned short h1 = f2bf_rne(r1);
    float f1 = __uint_as_float((unsigned)h1 << 16);
    float r2 = r1 - f1;
    unsigned short h2 = f2bf_rne(r2);
    s0 = h0; s1 = h1; s2 = h2;
}

// ---------------------------------------------------------------------------
// lengths + n_valid per batch
__global__ __launch_bounds__(256) void prep_lengths(const int* __restrict__ mask,
                                                    int* __restrict__ lengths,
                                                    int* __restrict__ nvalid) {
    int b = blockIdx.x;
    int t = threadIdx.x;
    int v = mask[b*LL + t] + mask[b*LL + 256 + t];
    #pragma unroll
    for (int off = 32; off; off >>= 1) v += __shfl_xor(v, off);
    __shared__ int red[4];
    if ((t & 63) == 0) red[t >> 6] = v;
    __syncthreads();
    if (t == 0) {
        int len = red[0] + red[1] + red[2] + red[3];
        lengths[b] = len;
        int nv = 0;
        #pragma unroll
        for (int p = 0; p < PP; ++p) nv += (len - p > 0) ? (len - p) : 0;
        nvalid[b] = nv;
    }
}

// ---------------------------------------------------------------------------
// A-splits: hidden (4096x768 f32) -> Aspl[3][4096][768] bf16
__global__ __launch_bounds__(256) void build_asplit(const float* __restrict__ hidden,
                                                    unsigned short* __restrict__ Aspl) {
    const size_t PLANE = (size_t)BL * GK;
    size_t base = ((size_t)blockIdx.x * 256 + threadIdx.x) * 4;
    float4 v = *(const float4*)(hidden + base);
    ushort4 p0, p1, p2;
    split3(v.x, p0.x, p1.x, p2.x);
    split3(v.y, p0.y, p1.y, p2.y);
    split3(v.z, p0.z, p1.z, p2.z);
    split3(v.w, p0.w, p1.w, p2.w);
    *(ushort4*)(Aspl + base)             = p0;
    *(ushort4*)(Aspl + PLANE + base)     = p1;
    *(ushort4*)(Aspl + 2 * PLANE + base) = p2;
}

// ---------------------------------------------------------------------------
// B-splits, TRANSPOSED: Bspl[3][2304 n][768 k] bf16, built directly from W1.
__global__ __launch_bounds__(256) void build_bsplit(const float* __restrict__ W1,
                                                    unsigned short* __restrict__ Bspl) {
    const size_t PLANE = (size_t)NCAT * GK;
    __shared__ float wv[16][65];
    int n0 = blockIdx.x * 16;
    int k0 = blockIdx.y * 64;
    int tx = threadIdx.x & 15;   // n offset (coalesced W1 read)
    int ty = threadIdx.x >> 4;   // k-quad
    int n = n0 + tx;
    #pragma unroll
    for (int j = 0; j < 4; ++j) {
        int k = k0 + ty * 4 + j;
        float w;
        if (n < HH) {
            w = W1[(size_t)k * HH + n] - W1[(size_t)(3*HH + k) * HH + n];
        } else if (n < 2 * HH) {
            int c = n - HH;
            w = W1[(size_t)(HH + k) * HH + c] + W1[(size_t)(3*HH + k) * HH + c];
        } else {
            int c = n - 2 * HH;
            w = W1[(size_t)(2*HH + k) * HH + c];
        }
        wv[tx][ty * 4 + j] = w;
    }
    __syncthreads();
    int n2 = threadIdx.x >> 4;   // 0..15
    int kq = threadIdx.x & 15;   // 0..15 (coalesced Bspl write)
    unsigned short e0[4], e1[4], e2[4];
    #pragma unroll
    for (int j = 0; j < 4; ++j)
        split3(wv[n2][kq * 4 + j], e0[j], e1[j], e2[j]);
    size_t off = (size_t)(n0 + n2) * GK + k0 + kq * 4;
    *(ushort4*)(Bspl + off)             = make_ushort4(e0[0], e0[1], e0[2], e0[3]);
    *(ushort4*)(Bspl + PLANE + off)     = make_ushort4(e1[0], e1[1], e1[2], e1[3]);
    *(ushort4*)(Bspl + 2 * PLANE + off) = make_ushort4(e2[0], e2[1], e2[2], e2[3]);
}

// ---------------------------------------------------------------------------
// bf16x3-split MFMA GEMM, 2-phase double-buffered (T3-minimum recipe):
// 128x128 tile, 4 waves (2x2 of 64x64), BK=64, flattened K-loop of 72 steps
// (6 terms x 12). STAGE(next) issued before compute(cur); ONE barrier/step
// (compiler emits vmcnt(0)+lgkmcnt(0) before s_barrier -> buffer handoff safe).
// XOR slot-swizzle slot^(row&7); global_load_lds w=16 with pre-swizzled src.
__global__ __launch_bounds__(256, 2) void gemm_mfma(const unsigned short* __restrict__ Aspl,
                                                    const unsigned short* __restrict__ Bspl,
                                                    float* __restrict__ C) {
    __shared__ __align__(16) unsigned short Asm[2][128 * 64];  // 32 KB
    __shared__ __align__(16) unsigned short Bsm[2][128 * 64];  // 32 KB
    const int tid  = threadIdx.x;
    const int wave = tid >> 6;
    const int lane = tid & 63;
    const int m0 = blockIdx.x * 128;
    const int n0 = blockIdx.y * 128;
    const int wr = wave >> 1;            // 0..1
    const int wc = wave & 1;             // 0..1
    const int srow = lane >> 3;          // 0..7 (row within 8-row stage group)
    const int slog = (lane & 7) ^ srow;  // logical k-slot this lane fetches
    const int l15 = lane & 15;
    const int g   = lane >> 4;           // 0..3
    const int r7  = l15 & 7;

    floatx4 acc[4][4];
    #pragma unroll
    for (int i = 0; i < 4; ++i)
        #pragma unroll
        for (int j = 0; j < 4; ++j) acc[i][j] = (floatx4)0.f;

    const size_t APL = (size_t)BL * GK;
    const size_t BPL = (size_t)NCAT * GK;

    // stage K-step kt into buffer buf (8 global_load_lds per lane, 32KB/block)
    auto stage = [&](int buf, int kt) {
        int t6   = kt / 12;                  // 0..5 (uniform, SALU)
        int k_in = (kt - t6 * 12) * 64;
        int a_sel = (t6 < 4) ? (t6 >> 1) : ((t6 == 4) ? 0 : 2);
        int b_sel = (t6 < 4) ? (t6 & 1)  : ((t6 == 4) ? 2 : 0);
        const unsigned short* Ab = Aspl + (size_t)a_sel * APL + (size_t)m0 * GK + k_in;
        const unsigned short* Bb = Bspl + (size_t)b_sel * BPL + (size_t)n0 * GK + k_in;
        #pragma unroll
        for (int j = 0; j < 4; ++j) {
            int base_r = (j * 4 + wave) * 8;
            const unsigned short* sa = Ab + (size_t)(base_r + srow) * GK + slog * 8;
            __builtin_amdgcn_global_load_lds(
                (const __attribute__((address_space(1))) void*)sa,
                (__attribute__((address_space(3))) void*)&Asm[buf][base_r * 64],
                16, 0, 0);
            const unsigned short* sb = Bb + (size_t)(base_r + srow) * GK + slog * 8;
            __builtin_amdgcn_global_load_lds(
                (const __attribute__((address_space(1))) void*)sb,
                (__attribute__((address_space(3))) void*)&Bsm[buf][base_r * 64],
                16, 0, 0);
        }
    };

    stage(0, 0);
    __syncthreads();   // drain prologue stage

    #pragma unroll 1
    for (int kt = 0; kt < 72; ++kt) {
        const int cur = kt & 1;
        if (kt < 71) stage(cur ^ 1, kt + 1);   // issue next-tile loads FIRST
        #pragma unroll
        for (int ks = 0; ks < 2; ++ks) {
            const int sph = ((ks * 4 + g) ^ r7) * 8;
            short8_t afr[4], bfr[4];
            #pragma unroll
            for (int mf = 0; mf < 4; ++mf)
                afr[mf] = *(const short8_t*)&Asm[cur][(wr * 64 + mf * 16 + l15) * 64 + sph];
            #pragma unroll
            for (int nf = 0; nf < 4; ++nf)
                bfr[nf] = *(const short8_t*)&Bsm[cur][(wc * 64 + nf * 16 + l15) * 64 + sph];
            #pragma unroll
            for (int mf = 0; mf < 4; ++mf)
                #pragma unroll
                for (int nf = 0; nf < 4; ++nf)
                    acc[mf][nf] = __builtin_amdgcn_mfma_f32_16x16x32_bf16(
                        afr[mf], bfr[nf], acc[mf][nf], 0, 0, 0);
        }
        __syncthreads();   // one barrier/step; auto vmcnt(0)+lgkmcnt(0) drain
    }

    // epilogue: D row = (lane>>4)*4 + reg, col = lane&15 (m89-verified layout)
    #pragma unroll
    for (int mf = 0; mf < 4; ++mf) {
        #pragma unroll
        for (int nf = 0; nf < 4; ++nf) {
            int col  = n0 + wc * 64 + nf * 16 + l15;
            int rowb = m0 + wr * 64 + mf * 16 + g * 4;
            #pragma unroll
            for (int e = 0; e < 4; ++e)
                C[(size_t)(rowb + e) * NCAT + col] = acc[mf][nf][e];
        }
    }
}

// ---------------------------------------------------------------------------
// scores(b,l,p) = w2 . relu(XA[l] + XB[l+p] + (sum_{t=l..l+p} Y[t])/(p+1) + b1) + b2
// one wave per (b,l); invalid -> -inf
__global__ __launch_bounds__(256) void score_kernel(const float* __restrict__ XO,
                                                    const float* __restrict__ b1,
                                                    const float* __restrict__ w2,
                                                    const float* __restrict__ b2,
                                                    const int* __restrict__ lengths,
                                                    float* __restrict__ sc) {
    int wid = (blockIdx.x * blockDim.x + threadIdx.x) >> 6;  // 0..4095
    int lane = threadIdx.x & 63;
    int b = wid >> 9, l = wid & (LL - 1);
    int len = lengths[b];
    float b2v = b2[0];

    const float* rowXA = XO + (size_t)wid * NCAT;
    float xa[12], sv[12], w2v[12];
    #pragma unroll
    for (int seg = 0; seg < 3; ++seg) {
        int h = seg * 256 + lane * 4;
        float4 a  = *(const float4*)(rowXA + h);
        float4 bb = *(const float4*)(b1 + h);
        float4 w  = *(const float4*)(w2 + h);
        xa[seg*4+0] = a.x + bb.x; xa[seg*4+1] = a.y + bb.y;
        xa[seg*4+2] = a.z + bb.z; xa[seg*4+3] = a.w + bb.w;
        w2v[seg*4+0] = w.x; w2v[seg*4+1] = w.y; w2v[seg*4+2] = w.z; w2v[seg*4+3] = w.w;
        sv[seg*4+0] = 0.f; sv[seg*4+1] = 0.f; sv[seg*4+2] = 0.f; sv[seg*4+3] = 0.f;
    }

    for (int p = 0; p < PP; ++p) {
        int j = l + p;
        float res = -INFINITY;
        if (j < len) {  // wave-uniform
            const float* rowj = XO + (size_t)(b * LL + j) * NCAT;
            float rs = 1.0f / (float)(p + 1);
            float part = 0.f;
            #pragma unroll
            for (int seg = 0; seg < 3; ++seg) {
                int h = seg * 256 + lane * 4;
                float4 xb = *(const float4*)(rowj + HH + h);
                float4 yv = *(const float4*)(rowj + 2*HH + h);
                sv[seg*4+0] += yv.x; sv[seg*4+1] += yv.y;
                sv[seg*4+2] += yv.z; sv[seg*4+3] += yv.w;
                float xbv[4] = {xb.x, xb.y, xb.z, xb.w};
                #pragma unroll
                for (int q = 0; q < 4; ++q) {
                    float pre = xa[seg*4+q] + xbv[q] + sv[seg*4+q] * rs;
                    part += fmaxf(pre, 0.f) * w2v[seg*4+q];
                }
            }
            #pragma unroll
            for (int off = 32; off; off >>= 1) part += __shfl_xor(part, off);
            res = part + b2v;
        }
        if (lane == 0) sc[(size_t)wid * PP + p] = res;
    }
}

// ---------------------------------------------------------------------------
// top-32 per batch: 1 wave, 64-bit keys in LDS, 40-chunk max hierarchy,
// fully wave-synchronous. Ties -> lower index (lax.top_k).
__device__ __forceinline__ unsigned long long wave_max_ull(unsigned long long v) {
    #pragma unroll
    for (int off = 32; off; off >>= 1) {
        unsigned long long o = __shfl_xor(v, off);
        if (o > v) v = o;
    }
    return v;
}
__global__ __launch_bounds__(64) void topk_kernel(const float* __restrict__ sc,
                                                  int* __restrict__ top_idx,
                                                  float* __restrict__ top_scores) {
    int b = blockIdx.x;
    int lane = threadIdx.x;
    __shared__ unsigned long long key[NSC];   // 20 KB
    __shared__ unsigned long long cmax[40];
    const float* scb = sc + (size_t)b * NSC;
    for (int j = 0; j < 40; ++j) {
        int i = j * 64 + lane;
        unsigned u = __float_as_uint(scb[i]);
        u = (u & 0x80000000u) ? ~u : (u | 0x80000000u);
        unsigned long long k = ((unsigned long long)u << 32) | (unsigned)(0xFFFFFFFFu - i);
        key[i] = k;
        unsigned long long mx = wave_max_ull(k);
        if (lane == 0) cmax[j] = mx;
    }
    for (int m = 0; m < MM; ++m) {
        unsigned long long v = (lane < 40) ? cmax[lane] : 0ull;
        unsigned long long best = wave_max_ull(v);
        int idx = (int)(0xFFFFFFFFu - (unsigned)(best & 0xFFFFFFFFull));
        if (lane == 0) {
            top_idx[b * MM + m]    = idx;
            top_scores[b * MM + m] = scb[idx];
            key[idx] = 0ull;
        }
        int c0 = idx >> 6;
        unsigned long long v2 = key[c0 * 64 + lane];
        unsigned long long mx2 = wave_max_ull(v2);
        if (lane == 0) cmax[c0] = mx2;
    }
}

// ---------------------------------------------------------------------------
// gathered mean features for selected phrases (direct <=5-row sum)
__global__ __launch_bounds__(256) void feats_kernel(const float* __restrict__ hidden,
                                                    const int* __restrict__ top_idx,
                                                    const int* __restrict__ nvalid,
                                                    float* __restrict__ feats) {
    int bm = blockIdx.x;            // 0..255
    int b = bm >> 5, m = bm & 31;
    int idx = top_idx[bm];
    int l = idx / PP, p = idx % PP;
    bool maskon = (m < nvalid[b]);
    float rs = 1.0f / (float)(p + 1);
    for (int h = threadIdx.x; h < HH; h += 256) {
        float sum = 0.f;
        if (maskon) {
            for (int t = l; t <= l + p; ++t)
                sum += hidden[((size_t)b * LL + t) * HH + h];
            sum *= rs;
        }
        feats[(size_t)bm * HH + h] = sum;
    }
}

// ---------------------------------------------------------------------------
// Wcomb[768][640] = [Wg1 | Wp]
__global__ __launch_bounds__(256) void build_wcomb(const float* __restrict__ Wg1,
                                                   const float* __restrict__ Wp,
                                                   float* __restrict__ Wcomb) {
    size_t idx4 = ((size_t)blockIdx.x * 256 + threadIdx.x) * 4;
    int k = (int)(idx4 / NTAIL);
    int c = (int)(idx4 % NTAIL);
    float4 v;
    if (c < 384) v = *(const float4*)(Wg1 + (size_t)k * 384 + c);
    else         v = *(const float4*)(Wp  + (size_t)k * DD  + (c - 384));
    *(float4*)(Wcomb + idx4) = v;
}

// ---------------------------------------------------------------------------
// tail GEMM: F(256x768) @ Wcomb(768x640). Tile 32x64, BK=64, 256 threads,
// 4 rows x 2 cols per thread. Epilogue: cols<384 -> tanh(+bg1) into G1;
// cols>=384 -> (+bp) into out_embeds. n0 is block-uniformly gate or embed.
__global__ __launch_bounds__(256) void tail_gemm(const float* __restrict__ F,
                                                 const float* __restrict__ Wcomb,
                                                 const float* __restrict__ bg1,
                                                 const float* __restrict__ bp,
                                                 float* __restrict__ G1,
                                                 float* __restrict__ out_embeds) {
    __shared__ __align__(16) float As[64][36];   // k-major A, stride 144B (16B-aligned)
    __shared__ __align__(16) float Bs[64][72];   // k-major B, stride 288B (16B-aligned)
    const int tid = threadIdx.x;
    const int m0 = blockIdx.x * 32;
    const int n0 = blockIdx.y * 64;
    const int ty = tid >> 5;     // 0..7  -> rows ty*4..ty*4+3
    const int tx = tid & 31;     // 0..31 -> cols tx*2, tx*2+1

    float acc[4][2];
    #pragma unroll
    for (int r = 0; r < 4; ++r) { acc[r][0] = 0.f; acc[r][1] = 0.f; }

    // staging maps
    const int ar = tid >> 3;           // 0..31 (A row)
    const int ac = (tid & 7) * 4;      // 0,4,...,28 (A col base, two halves)
    const int br = tid >> 4;           // 0..15 (B row base, 4 groups of 16)
    const int bc = (tid & 15) * 4;     // 0..60

    for (int kt = 0; kt < GK; kt += 64) {
        float4 a0 = *(const float4*)(F + (size_t)(m0 + ar) * GK + kt + ac);
        float4 a1 = *(const float4*)(F + (size_t)(m0 + ar) * GK + kt + ac + 32);
        float4 bv[4];
        #pragma unroll
        for (int jj = 0; jj < 4; ++jj)
            bv[jj] = *(const float4*)(Wcomb + (size_t)(kt + jj * 16 + br) * NTAIL + n0 + bc);
        __syncthreads();
        As[ac+0][ar] = a0.x; As[ac+1][ar] = a0.y; As[ac+2][ar] = a0.z; As[ac+3][ar] = a0.w;
        As[ac+32][ar] = a1.x; As[ac+33][ar] = a1.y; As[ac+34][ar] = a1.z; As[ac+35][ar] = a1.w;
        #pragma unroll
        for (int jj = 0; jj < 4; ++jj)
            *(float4*)&Bs[jj * 16 + br][bc] = bv[jj];
        __syncthreads();
        #pragma unroll
        for (int k = 0; k < 64; ++k) {
            float4 a = *(const float4*)&As[k][ty * 4];
            float2 bvv = *(const float2*)&Bs[k][tx * 2];
            acc[0][0] = fmaf(a.x, bvv.x, acc[0][0]);
            acc[0][1] = fmaf(a.x, bvv.y, acc[0][1]);
            acc[1][0] = fmaf(a.y, bvv.x, acc[1][0]);
            acc[1][1] = fmaf(a.y, bvv.y, acc[1][1]);
            acc[2][0] = fmaf(a.z, bvv.x, acc[2][0]);
            acc[2][1] = fmaf(a.z, bvv.y, acc[2][1]);
            acc[3][0] = fmaf(a.w, bvv.x, acc[3][0]);
            acc[3][1] = fmaf(a.w, bvv.y, acc[3][1]);
        }
    }
    #pragma unroll
    for (int r = 0; r < 4; ++r) {
        int row = m0 + ty * 4 + r;
        #pragma unroll
        for (int c = 0; c < 2; ++c) {
            int col = n0 + tx * 2 + c;
            if (col < 384) {
                G1[(size_t)row * 384 + col] = tanhf(acc[r][c] + bg1[col]);
            } else {
                int d = col - 384;
                out_embeds[(size_t)row * DD + d] = acc[r][c] + bp[d];
            }
        }
    }
}

// ---------------------------------------------------------------------------
// gate[row] = wg2 . G1[row] + bg2 ; one wave per row
__global__ __launch_bounds__(256) void gate_reduce(const float* __restrict__ G1,
                                                   const float* __restrict__ wg2,
                                                   const float* __restrict__ bg2,
                                                   float* __restrict__ gate) {
    int row = blockIdx.x * 4 + (threadIdx.x >> 6);
    int lane = threadIdx.x & 63;
    float part = 0.f;
    #pragma unroll
    for (int seg = 0; seg < 6; ++seg) {
        int c = seg * 64 + lane;
        part = fmaf(G1[(size_t)row * 384 + c], wg2[c], part);
    }
    #pragma unroll
    for (int off = 32; off; off >>= 1) part += __shfl_xor(part, off);
    if (lane == 0) gate[row] = part + bg2[0];
}

// ---------------------------------------------------------------------------
// masks, masked softmax of gate, masked scores
__global__ __launch_bounds__(64) void finalize_kernel(const float* __restrict__ gate,
                                                      const float* __restrict__ top_scores,
                                                      const int* __restrict__ nvalid,
                                                      float* __restrict__ out_masks,
                                                      float* __restrict__ out_attn,
                                                      float* __restrict__ out_scores) {
    int b = blockIdx.x;
    int t = threadIdx.x;
    bool live = (t < MM);
    bool maskon = live && (t < nvalid[b]);
    float g = maskon ? gate[b * MM + t] : -INFINITY;
    float mx = g;
    #pragma unroll
    for (int off = 16; off; off >>= 1) mx = fmaxf(mx, __shfl_xor(mx, off));
    float e = (g == -INFINITY) ? 0.f : expf(g - mx);
    float ssum = e;
    #pragma unroll
    for (int off = 16; off; off >>= 1) ssum += __shfl_xor(ssum, off);
    if (live) {
        out_masks[b * MM + t]  = maskon ? 1.0f : 0.0f;
        out_attn[b * MM + t]   = e / ssum;
        out_scores[b * MM + t] = maskon ? top_scores[b * MM + t] : -INFINITY;
    }
}

// ---------------------------------------------------------------------------
extern "C" void kernel_launch(void* const* d_in, const int* in_sizes, int n_in,
                              void* d_out, int out_size, void* d_ws, size_t ws_size,
                              hipStream_t stream) {
    const float* hidden = (const float*)d_in[0];
    const int*   amask  = (const int*)  d_in[1];
    const float* W1     = (const float*)d_in[2];
    const float* b1     = (const float*)d_in[3];
    const float* w2     = (const float*)d_in[4];
    const float* b2     = (const float*)d_in[5];
    const float* Wg1    = (const float*)d_in[6];
    const float* bg1    = (const float*)d_in[7];
    const float* wg2    = (const float*)d_in[8];
    const float* bg2    = (const float*)d_in[9];
    const float* Wp     = (const float*)d_in[10];
    const float* bp     = (const float*)d_in[11];

    float* out = (float*)d_out;
    float* out_embeds = out;                       // 8*32*256 = 65536
    float* out_masks  = out + 65536;               // 256
    float* out_attn   = out + 65792;               // 256
    float* out_scores = out + 66048;               // 256

    // workspace layout
    unsigned short* Aspl = (unsigned short*)d_ws;              // 3*4096*768 bf16
    unsigned short* Bspl = Aspl + (size_t)3 * BL * GK;         // 3*2304*768 bf16
    float* XO     = (float*)(Bspl + (size_t)3 * NCAT * GK);    // 4096*2304 f32
    float* scbuf  = XO + (size_t)BL * NCAT;                    // 8*2560
    float* gate   = scbuf + (size_t)BB * NSC;                  // 256
    float* tscore = gate + BB * MM;                            // 256
    int*   tidx    = (int*)(tscore + BB * MM);                 // 256
    int*   lengths = tidx + BB * MM;                           // 8
    int*   nvalid  = lengths + BB;                             // 8
    // tail scratch ALIASED into XO (dead after score_kernel):
    float* feats  = XO;                                        // 256*768
    float* Wcomb  = XO + (size_t)BB * MM * HH;                 // 768*640
    float* G1     = Wcomb + (size_t)GK * NTAIL;                // 256*384

    prep_lengths<<<BB, 256, 0, stream>>>(amask, lengths, nvalid);

    build_asplit<<<(BL * GK / 4) / 256, 256, 0, stream>>>(hidden, Aspl);

    {
        dim3 grid(NCAT / 16, GK / 64);   // 144 x 12
        build_bsplit<<<grid, 256, 0, stream>>>(W1, Bspl);
    }

    {
        dim3 grid(BL / 128, NCAT / 128);   // 32 x 18
        gemm_mfma<<<grid, 256, 0, stream>>>(Aspl, Bspl, XO);
    }

    score_kernel<<<(BL * 64) / 256, 256, 0, stream>>>(XO, b1, w2, b2, lengths, scbuf);

    topk_kernel<<<BB, 64, 0, stream>>>(scbuf, tidx, tscore);

    // XO is dead from here; feats/Wcomb/G1 alias it
    build_wcomb<<<(GK * NTAIL / 4) / 256, 256, 0, stream>>>(Wg1, Wp, Wcomb);

    feats_kernel<<<BB * MM, 256, 0, stream>>>(hidden, tidx, nvalid, feats);

    {
        dim3 grid(BB * MM / 32, NTAIL / 64);   // 8 x 10
        tail_gemm<<<grid, 256, 0, stream>>>(feats, Wcomb, bg1, bp, G1, out_embeds);
    }

    gate_reduce<<<BB * MM / 4, 256, 0, stream>>>(G1, wg2, bg2, gate);

    finalize_kernel<<<BB, 64, 0, stream>>>(gate, tscore, nvalid, out_masks, out_attn, out_scores);
}

// Round 5
// 218.531 us; speedup vs baseline: 1.3243x; 1.2389x over previous
//
#include <hip/hip_runtime.h>
#include <math.h>

// Problem constants
#define BB 8
#define LL 512
#define HH 768
#define PP 5
#define MM 32
#define DD 256
#define BL (BB*LL)          // 4096 rows
#define NCAT (3*HH)         // 2304 GEMM output cols
#define NSC (LL*PP)         // 2560 scores per batch
#define GK HH               // per-term K = 768
#define NTAIL 640           // tail GEMM cols: 384 gate + 256 embed

typedef short short8_t __attribute__((ext_vector_type(8)));
typedef float floatx4  __attribute__((ext_vector_type(4)));

// ---------------------------------------------------------------------------
// bf16 helpers (RNE)
__device__ __forceinline__ unsigned short f2bf_rne(float x) {
    unsigned u = __float_as_uint(x);
    unsigned r = u + 0x7FFFu + ((u >> 16) & 1u);
    return (unsigned short)(r >> 16);
}
__device__ __forceinline__ void split3(float x, unsigned short& s0,
                                       unsigned short& s1, unsigned short& s2) {
    unsigned short h0 = f2bf_rne(x);
    float f0 = __uint_as_float((unsigned)h0 << 16);
    float r1 = x - f0;
    unsigned short h1 = f2bf_rne(r1);
    float f1 = __uint_as_float((unsigned)h1 << 16);
    float r2 = r1 - f1;
    unsigned short h2 = f2bf_rne(r2);
    s0 = h0; s1 = h1; s2 = h2;
}

// ---------------------------------------------------------------------------
// lengths + n_valid per batch
__global__ __launch_bounds__(256) void prep_lengths(const int* __restrict__ mask,
                                                    int* __restrict__ lengths,
                                                    int* __restrict__ nvalid) {
    int b = blockIdx.x;
    int t = threadIdx.x;
    int v = mask[b*LL + t] + mask[b*LL + 256 + t];
    #pragma unroll
    for (int off = 32; off; off >>= 1) v += __shfl_xor(v, off);
    __shared__ int red[4];
    if ((t & 63) == 0) red[t >> 6] = v;
    __syncthreads();
    if (t == 0) {
        int len = red[0] + red[1] + red[2] + red[3];
        lengths[b] = len;
        int nv = 0;
        #pragma unroll
        for (int p = 0; p < PP; ++p) nv += (len - p > 0) ? (len - p) : 0;
        nvalid[b] = nv;
    }
}

// ---------------------------------------------------------------------------
// A-splits: hidden (4096x768 f32) -> Aspl[3][4096][768] bf16
__global__ __launch_bounds__(256) void build_asplit(const float* __restrict__ hidden,
                                                    unsigned short* __restrict__ Aspl) {
    const size_t PLANE = (size_t)BL * GK;
    size_t base = ((size_t)blockIdx.x * 256 + threadIdx.x) * 4;
    float4 v = *(const float4*)(hidden + base);
    ushort4 p0, p1, p2;
    split3(v.x, p0.x, p1.x, p2.x);
    split3(v.y, p0.y, p1.y, p2.y);
    split3(v.z, p0.z, p1.z, p2.z);
    split3(v.w, p0.w, p1.w, p2.w);
    *(ushort4*)(Aspl + base)             = p0;
    *(ushort4*)(Aspl + PLANE + base)     = p1;
    *(ushort4*)(Aspl + 2 * PLANE + base) = p2;
}

// ---------------------------------------------------------------------------
// B-splits, TRANSPOSED: Bspl[3][2304 n][768 k] bf16, built directly from W1.
__global__ __launch_bounds__(256) void build_bsplit(const float* __restrict__ W1,
                                                    unsigned short* __restrict__ Bspl) {
    const size_t PLANE = (size_t)NCAT * GK;
    __shared__ float wv[16][65];
    int n0 = blockIdx.x * 16;
    int k0 = blockIdx.y * 64;
    int tx = threadIdx.x & 15;   // n offset (coalesced W1 read)
    int ty = threadIdx.x >> 4;   // k-quad
    int n = n0 + tx;
    #pragma unroll
    for (int j = 0; j < 4; ++j) {
        int k = k0 + ty * 4 + j;
        float w;
        if (n < HH) {
            w = W1[(size_t)k * HH + n] - W1[(size_t)(3*HH + k) * HH + n];
        } else if (n < 2 * HH) {
            int c = n - HH;
            w = W1[(size_t)(HH + k) * HH + c] + W1[(size_t)(3*HH + k) * HH + c];
        } else {
            int c = n - 2 * HH;
            w = W1[(size_t)(2*HH + k) * HH + c];
        }
        wv[tx][ty * 4 + j] = w;
    }
    __syncthreads();
    int n2 = threadIdx.x >> 4;   // 0..15
    int kq = threadIdx.x & 15;   // 0..15 (coalesced Bspl write)
    unsigned short e0[4], e1[4], e2[4];
    #pragma unroll
    for (int j = 0; j < 4; ++j)
        split3(wv[n2][kq * 4 + j], e0[j], e1[j], e2[j]);
    size_t off = (size_t)(n0 + n2) * GK + k0 + kq * 4;
    *(ushort4*)(Bspl + off)             = make_ushort4(e0[0], e0[1], e0[2], e0[3]);
    *(ushort4*)(Bspl + PLANE + off)     = make_ushort4(e1[0], e1[1], e1[2], e1[3]);
    *(ushort4*)(Bspl + 2 * PLANE + off) = make_ushort4(e2[0], e2[1], e2[2], e2[3]);
}

// ---------------------------------------------------------------------------
// bf16x3-split MFMA GEMM: XO = sum over 6 term-products of Aspl x Bspl^T
// EXACT round-2 structure (local optimum): 128x128 tile, BK=64, 4 waves
// (2x2 of 64x64), single 32KB LDS buffers, stage-barrier-compute per K-step.
// R3 (2-wave) and R4 (64KB dbuf) both regressed via occupancy loss (m132).
// XOR slot-swizzle slot^(row&7); global_load_lds w=16 with pre-swizzled src.
__global__ __launch_bounds__(256) void gemm_mfma(const unsigned short* __restrict__ Aspl,
                                                 const unsigned short* __restrict__ Bspl,
                                                 float* __restrict__ C) {
    __shared__ __align__(16) unsigned short Asm[128 * 64];
    __shared__ __align__(16) unsigned short Bsm[128 * 64];
    const int tid  = threadIdx.x;
    const int wave = tid >> 6;
    const int lane = tid & 63;
    const int m0 = blockIdx.x * 128;
    const int n0 = blockIdx.y * 128;
    const int wr = wave >> 1;            // 0..1
    const int wc = wave & 1;             // 0..1
    const int srow = lane >> 3;          // 0..7 (row within 8-row stage group)
    const int slog = (lane & 7) ^ srow;  // logical k-slot this lane fetches
    const int l15 = lane & 15;
    const int g   = lane >> 4;           // 0..3
    const int r7  = l15 & 7;

    floatx4 acc[4][4];
    #pragma unroll
    for (int i = 0; i < 4; ++i)
        #pragma unroll
        for (int j = 0; j < 4; ++j) acc[i][j] = (floatx4)0.f;

    const size_t APL = (size_t)BL * GK;
    const size_t BPL = (size_t)NCAT * GK;

    #pragma unroll 1
    for (int t = 0; t < 6; ++t) {
        // term selects: a = {0,0,1,1,0,2}, b = {0,1,0,1,2,0}
        const int a_sel = (t < 4) ? (t >> 1) : ((t == 4) ? 0 : 2);
        const int b_sel = (t < 4) ? (t & 1)  : ((t == 4) ? 2 : 0);
        const unsigned short* Ab = Aspl + (size_t)a_sel * APL + (size_t)m0 * GK;
        const unsigned short* Bb = Bspl + (size_t)b_sel * BPL + (size_t)n0 * GK;
        #pragma unroll 1
        for (int kt = 0; kt < GK; kt += 64) {
            __syncthreads();   // previous compute done before overwrite
            #pragma unroll
            for (int j = 0; j < 4; ++j) {
                int base_r = (j * 4 + wave) * 8;
                const unsigned short* sa = Ab + (size_t)(base_r + srow) * GK + kt + slog * 8;
                __builtin_amdgcn_global_load_lds(
                    (const __attribute__((address_space(1))) void*)sa,
                    (__attribute__((address_space(3))) void*)&Asm[base_r * 64],
                    16, 0, 0);
                const unsigned short* sb = Bb + (size_t)(base_r + srow) * GK + kt + slog * 8;
                __builtin_amdgcn_global_load_lds(
                    (const __attribute__((address_space(1))) void*)sb,
                    (__attribute__((address_space(3))) void*)&Bsm[base_r * 64],
                    16, 0, 0);
            }
            __syncthreads();   // compiler drains vmcnt(0) before this barrier
            #pragma unroll
            for (int ks = 0; ks < 2; ++ks) {
                const int sph = ((ks * 4 + g) ^ r7) * 8;
                short8_t afr[4], bfr[4];
                #pragma unroll
                for (int mf = 0; mf < 4; ++mf)
                    afr[mf] = *(const short8_t*)&Asm[(wr * 64 + mf * 16 + l15) * 64 + sph];
                #pragma unroll
                for (int nf = 0; nf < 4; ++nf)
                    bfr[nf] = *(const short8_t*)&Bsm[(wc * 64 + nf * 16 + l15) * 64 + sph];
                #pragma unroll
                for (int mf = 0; mf < 4; ++mf)
                    #pragma unroll
                    for (int nf = 0; nf < 4; ++nf)
                        acc[mf][nf] = __builtin_amdgcn_mfma_f32_16x16x32_bf16(
                            afr[mf], bfr[nf], acc[mf][nf], 0, 0, 0);
            }
        }
    }
    // epilogue: D row = (lane>>4)*4 + reg, col = lane&15 (m89-verified layout)
    #pragma unroll
    for (int mf = 0; mf < 4; ++mf) {
        #pragma unroll
        for (int nf = 0; nf < 4; ++nf) {
            int col  = n0 + wc * 64 + nf * 16 + l15;
            int rowb = m0 + wr * 64 + mf * 16 + g * 4;
            #pragma unroll
            for (int e = 0; e < 4; ++e)
                C[(size_t)(rowb + e) * NCAT + col] = acc[mf][nf][e];
        }
    }
}

// ---------------------------------------------------------------------------
// scores(b,l,p) = w2 . relu(XA[l] + XB[l+p] + (sum_{t=l..l+p} Y[t])/(p+1) + b1) + b2
// one wave per (b,l); invalid -> -inf
__global__ __launch_bounds__(256) void score_kernel(const float* __restrict__ XO,
                                                    const float* __restrict__ b1,
                                                    const float* __restrict__ w2,
                                                    const float* __restrict__ b2,
                                                    const int* __restrict__ lengths,
                                                    float* __restrict__ sc) {
    int wid = (blockIdx.x * blockDim.x + threadIdx.x) >> 6;  // 0..4095
    int lane = threadIdx.x & 63;
    int b = wid >> 9, l = wid & (LL - 1);
    int len = lengths[b];
    float b2v = b2[0];

    const float* rowXA = XO + (size_t)wid * NCAT;
    float xa[12], sv[12], w2v[12];
    #pragma unroll
    for (int seg = 0; seg < 3; ++seg) {
        int h = seg * 256 + lane * 4;
        float4 a  = *(const float4*)(rowXA + h);
        float4 bb = *(const float4*)(b1 + h);
        float4 w  = *(const float4*)(w2 + h);
        xa[seg*4+0] = a.x + bb.x; xa[seg*4+1] = a.y + bb.y;
        xa[seg*4+2] = a.z + bb.z; xa[seg*4+3] = a.w + bb.w;
        w2v[seg*4+0] = w.x; w2v[seg*4+1] = w.y; w2v[seg*4+2] = w.z; w2v[seg*4+3] = w.w;
        sv[seg*4+0] = 0.f; sv[seg*4+1] = 0.f; sv[seg*4+2] = 0.f; sv[seg*4+3] = 0.f;
    }

    for (int p = 0; p < PP; ++p) {
        int j = l + p;
        float res = -INFINITY;
        if (j < len) {  // wave-uniform
            const float* rowj = XO + (size_t)(b * LL + j) * NCAT;
            float rs = 1.0f / (float)(p + 1);
            float part = 0.f;
            #pragma unroll
            for (int seg = 0; seg < 3; ++seg) {
                int h = seg * 256 + lane * 4;
                float4 xb = *(const float4*)(rowj + HH + h);
                float4 yv = *(const float4*)(rowj + 2*HH + h);
                sv[seg*4+0] += yv.x; sv[seg*4+1] += yv.y;
                sv[seg*4+2] += yv.z; sv[seg*4+3] += yv.w;
                float xbv[4] = {xb.x, xb.y, xb.z, xb.w};
                #pragma unroll
                for (int q = 0; q < 4; ++q) {
                    float pre = xa[seg*4+q] + xbv[q] + sv[seg*4+q] * rs;
                    part += fmaxf(pre, 0.f) * w2v[seg*4+q];
                }
            }
            #pragma unroll
            for (int off = 32; off; off >>= 1) part += __shfl_xor(part, off);
            res = part + b2v;
        }
        if (lane == 0) sc[(size_t)wid * PP + p] = res;
    }
}

// ---------------------------------------------------------------------------
// top-32 per batch: 1 wave, 64-bit keys in LDS, 40-chunk max hierarchy,
// fully wave-synchronous. Ties -> lower index (lax.top_k).
__device__ __forceinline__ unsigned long long wave_max_ull(unsigned long long v) {
    #pragma unroll
    for (int off = 32; off; off >>= 1) {
        unsigned long long o = __shfl_xor(v, off);
        if (o > v) v = o;
    }
    return v;
}
__global__ __launch_bounds__(64) void topk_kernel(const float* __restrict__ sc,
                                                  int* __restrict__ top_idx,
                                                  float* __restrict__ top_scores) {
    int b = blockIdx.x;
    int lane = threadIdx.x;
    __shared__ unsigned long long key[NSC];   // 20 KB
    __shared__ unsigned long long cmax[40];
    const float* scb = sc + (size_t)b * NSC;
    for (int j = 0; j < 40; ++j) {
        int i = j * 64 + lane;
        unsigned u = __float_as_uint(scb[i]);
        u = (u & 0x80000000u) ? ~u : (u | 0x80000000u);
        unsigned long long k = ((unsigned long long)u << 32) | (unsigned)(0xFFFFFFFFu - i);
        key[i] = k;
        unsigned long long mx = wave_max_ull(k);
        if (lane == 0) cmax[j] = mx;
    }
    for (int m = 0; m < MM; ++m) {
        unsigned long long v = (lane < 40) ? cmax[lane] : 0ull;
        unsigned long long best = wave_max_ull(v);
        int idx = (int)(0xFFFFFFFFu - (unsigned)(best & 0xFFFFFFFFull));
        if (lane == 0) {
            top_idx[b * MM + m]    = idx;
            top_scores[b * MM + m] = scb[idx];
            key[idx] = 0ull;
        }
        int c0 = idx >> 6;
        unsigned long long v2 = key[c0 * 64 + lane];
        unsigned long long mx2 = wave_max_ull(v2);
        if (lane == 0) cmax[c0] = mx2;
    }
}

// ---------------------------------------------------------------------------
// gathered mean features for selected phrases (direct <=5-row sum)
__global__ __launch_bounds__(256) void feats_kernel(const float* __restrict__ hidden,
                                                    const int* __restrict__ top_idx,
                                                    const int* __restrict__ nvalid,
                                                    float* __restrict__ feats) {
    int bm = blockIdx.x;            // 0..255
    int b = bm >> 5, m = bm & 31;
    int idx = top_idx[bm];
    int l = idx / PP, p = idx % PP;
    bool maskon = (m < nvalid[b]);
    float rs = 1.0f / (float)(p + 1);
    for (int h = threadIdx.x; h < HH; h += 256) {
        float sum = 0.f;
        if (maskon) {
            for (int t = l; t <= l + p; ++t)
                sum += hidden[((size_t)b * LL + t) * HH + h];
            sum *= rs;
        }
        feats[(size_t)bm * HH + h] = sum;
    }
}

// ---------------------------------------------------------------------------
// Wcomb[768][640] = [Wg1 | Wp]
__global__ __launch_bounds__(256) void build_wcomb(const float* __restrict__ Wg1,
                                                   const float* __restrict__ Wp,
                                                   float* __restrict__ Wcomb) {
    size_t idx4 = ((size_t)blockIdx.x * 256 + threadIdx.x) * 4;
    int k = (int)(idx4 / NTAIL);
    int c = (int)(idx4 % NTAIL);
    float4 v;
    if (c < 384) v = *(const float4*)(Wg1 + (size_t)k * 384 + c);
    else         v = *(const float4*)(Wp  + (size_t)k * DD  + (c - 384));
    *(float4*)(Wcomb + idx4) = v;
}

// ---------------------------------------------------------------------------
// tail GEMM: F(256x768) @ Wcomb(768x640). Tile 32x64, BK=64, 256 threads,
// 4 rows x 2 cols per thread. Epilogue: cols<384 -> tanh(+bg1) into G1;
// cols>=384 -> (+bp) into out_embeds.
__global__ __launch_bounds__(256) void tail_gemm(const float* __restrict__ F,
                                                 const float* __restrict__ Wcomb,
                                                 const float* __restrict__ bg1,
                                                 const float* __restrict__ bp,
                                                 float* __restrict__ G1,
                                                 float* __restrict__ out_embeds) {
    __shared__ __align__(16) float As[64][36];   // k-major A
    __shared__ __align__(16) float Bs[64][72];   // k-major B
    const int tid = threadIdx.x;
    const int m0 = blockIdx.x * 32;
    const int n0 = blockIdx.y * 64;
    const int ty = tid >> 5;     // 0..7  -> rows ty*4..ty*4+3
    const int tx = tid & 31;     // 0..31 -> cols tx*2, tx*2+1

    float acc[4][2];
    #pragma unroll
    for (int r = 0; r < 4; ++r) { acc[r][0] = 0.f; acc[r][1] = 0.f; }

    const int ar = tid >> 3;           // 0..31 (A row)
    const int ac = (tid & 7) * 4;      // 0,4,...,28 (A col base, two halves)
    const int br = tid >> 4;           // 0..15 (B row base, 4 groups of 16)
    const int bc = (tid & 15) * 4;     // 0..60

    for (int kt = 0; kt < GK; kt += 64) {
        float4 a0 = *(const float4*)(F + (size_t)(m0 + ar) * GK + kt + ac);
        float4 a1 = *(const float4*)(F + (size_t)(m0 + ar) * GK + kt + ac + 32);
        float4 bv[4];
        #pragma unroll
        for (int jj = 0; jj < 4; ++jj)
            bv[jj] = *(const float4*)(Wcomb + (size_t)(kt + jj * 16 + br) * NTAIL + n0 + bc);
        __syncthreads();
        As[ac+0][ar] = a0.x; As[ac+1][ar] = a0.y; As[ac+2][ar] = a0.z; As[ac+3][ar] = a0.w;
        As[ac+32][ar] = a1.x; As[ac+33][ar] = a1.y; As[ac+34][ar] = a1.z; As[ac+35][ar] = a1.w;
        #pragma unroll
        for (int jj = 0; jj < 4; ++jj)
            *(float4*)&Bs[jj * 16 + br][bc] = bv[jj];
        __syncthreads();
        #pragma unroll
        for (int k = 0; k < 64; ++k) {
            float4 a = *(const float4*)&As[k][ty * 4];
            float2 bvv = *(const float2*)&Bs[k][tx * 2];
            acc[0][0] = fmaf(a.x, bvv.x, acc[0][0]);
            acc[0][1] = fmaf(a.x, bvv.y, acc[0][1]);
            acc[1][0] = fmaf(a.y, bvv.x, acc[1][0]);
            acc[1][1] = fmaf(a.y, bvv.y, acc[1][1]);
            acc[2][0] = fmaf(a.z, bvv.x, acc[2][0]);
            acc[2][1] = fmaf(a.z, bvv.y, acc[2][1]);
            acc[3][0] = fmaf(a.w, bvv.x, acc[3][0]);
            acc[3][1] = fmaf(a.w, bvv.y, acc[3][1]);
        }
    }
    #pragma unroll
    for (int r = 0; r < 4; ++r) {
        int row = m0 + ty * 4 + r;
        #pragma unroll
        for (int c = 0; c < 2; ++c) {
            int col = n0 + tx * 2 + c;
            if (col < 384) {
                G1[(size_t)row * 384 + col] = tanhf(acc[r][c] + bg1[col]);
            } else {
                int d = col - 384;
                out_embeds[(size_t)row * DD + d] = acc[r][c] + bp[d];
            }
        }
    }
}

// ---------------------------------------------------------------------------
// gate[row] = wg2 . G1[row] + bg2 ; one wave per row
__global__ __launch_bounds__(256) void gate_reduce(const float* __restrict__ G1,
                                                   const float* __restrict__ wg2,
                                                   const float* __restrict__ bg2,
                                                   float* __restrict__ gate) {
    int row = blockIdx.x * 4 + (threadIdx.x >> 6);
    int lane = threadIdx.x & 63;
    float part = 0.f;
    #pragma unroll
    for (int seg = 0; seg < 6; ++seg) {
        int c = seg * 64 + lane;
        part = fmaf(G1[(size_t)row * 384 + c], wg2[c], part);
    }
    #pragma unroll
    for (int off = 32; off; off >>= 1) part += __shfl_xor(part, off);
    if (lane == 0) gate[row] = part + bg2[0];
}

// ---------------------------------------------------------------------------
// masks, masked softmax of gate, masked scores
__global__ __launch_bounds__(64) void finalize_kernel(const float* __restrict__ gate,
                                                      const float* __restrict__ top_scores,
                                                      const int* __restrict__ nvalid,
                                                      float* __restrict__ out_masks,
                                                      float* __restrict__ out_attn,
                                                      float* __restrict__ out_scores) {
    int b = blockIdx.x;
    int t = threadIdx.x;
    bool live = (t < MM);
    bool maskon = live && (t < nvalid[b]);
    float g = maskon ? gate[b * MM + t] : -INFINITY;
    float mx = g;
    #pragma unroll
    for (int off = 16; off; off >>= 1) mx = fmaxf(mx, __shfl_xor(mx, off));
    float e = (g == -INFINITY) ? 0.f : expf(g - mx);
    float ssum = e;
    #pragma unroll
    for (int off = 16; off; off >>= 1) ssum += __shfl_xor(ssum, off);
    if (live) {
        out_masks[b * MM + t]  = maskon ? 1.0f : 0.0f;
        out_attn[b * MM + t]   = e / ssum;
        out_scores[b * MM + t] = maskon ? top_scores[b * MM + t] : -INFINITY;
    }
}

// ---------------------------------------------------------------------------
extern "C" void kernel_launch(void* const* d_in, const int* in_sizes, int n_in,
                              void* d_out, int out_size, void* d_ws, size_t ws_size,
                              hipStream_t stream) {
    const float* hidden = (const float*)d_in[0];
    const int*   amask  = (const int*)  d_in[1];
    const float* W1     = (const float*)d_in[2];
    const float* b1     = (const float*)d_in[3];
    const float* w2     = (const float*)d_in[4];
    const float* b2     = (const float*)d_in[5];
    const float* Wg1    = (const float*)d_in[6];
    const float* bg1    = (const float*)d_in[7];
    const float* wg2    = (const float*)d_in[8];
    const float* bg2    = (const float*)d_in[9];
    const float* Wp     = (const float*)d_in[10];
    const float* bp     = (const float*)d_in[11];

    float* out = (float*)d_out;
    float* out_embeds = out;                       // 8*32*256 = 65536
    float* out_masks  = out + 65536;               // 256
    float* out_attn   = out + 65792;               // 256
    float* out_scores = out + 66048;               // 256

    // workspace layout
    unsigned short* Aspl = (unsigned short*)d_ws;              // 3*4096*768 bf16
    unsigned short* Bspl = Aspl + (size_t)3 * BL * GK;         // 3*2304*768 bf16
    float* XO     = (float*)(Bspl + (size_t)3 * NCAT * GK);    // 4096*2304 f32
    float* scbuf  = XO + (size_t)BL * NCAT;                    // 8*2560
    float* gate   = scbuf + (size_t)BB * NSC;                  // 256
    float* tscore = gate + BB * MM;                            // 256
    int*   tidx    = (int*)(tscore + BB * MM);                 // 256
    int*   lengths = tidx + BB * MM;                           // 8
    int*   nvalid  = lengths + BB;                             // 8
    // tail scratch ALIASED into XO (dead after score_kernel):
    float* feats  = XO;                                        // 256*768
    float* Wcomb  = XO + (size_t)BB * MM * HH;                 // 768*640
    float* G1     = Wcomb + (size_t)GK * NTAIL;                // 256*384

    prep_lengths<<<BB, 256, 0, stream>>>(amask, lengths, nvalid);

    build_asplit<<<(BL * GK / 4) / 256, 256, 0, stream>>>(hidden, Aspl);

    {
        dim3 grid(NCAT / 16, GK / 64);   // 144 x 12
        build_bsplit<<<grid, 256, 0, stream>>>(W1, Bspl);
    }

    {
        dim3 grid(BL / 128, NCAT / 128);   // 32 x 18
        gemm_mfma<<<grid, 256, 0, stream>>>(Aspl, Bspl, XO);
    }

    score_kernel<<<(BL * 64) / 256, 256, 0, stream>>>(XO, b1, w2, b2, lengths, scbuf);

    topk_kernel<<<BB, 64, 0, stream>>>(scbuf, tidx, tscore);

    // XO is dead from here; feats/Wcomb/G1 alias it
    build_wcomb<<<(GK * NTAIL / 4) / 256, 256, 0, stream>>>(Wg1, Wp, Wcomb);

    feats_kernel<<<BB * MM, 256, 0, stream>>>(hidden, tidx, nvalid, feats);

    {
        dim3 grid(BB * MM / 32, NTAIL / 64);   // 8 x 10
        tail_gemm<<<grid, 256, 0, stream>>>(feats, Wcomb, bg1, bp, G1, out_embeds);
    }

    gate_reduce<<<BB * MM / 4, 256, 0, stream>>>(G1, wg2, bg2, gate);

    finalize_kernel<<<BB, 64, 0, stream>>>(gate, tscore, nvalid, out_masks, out_attn, out_scores);
}